// Round 6
// baseline (528.726 us; speedup 1.0000x reference)
//
#include <hip/hip_runtime.h>
#include <hip/hip_bf16.h>

typedef __attribute__((ext_vector_type(8))) short short8;
typedef __attribute__((ext_vector_type(4))) short short4v;
typedef __attribute__((ext_vector_type(4))) float floatx4;

#define EDIM 256
#define HDIM 512
#define LDIM 16
#define NCHAIN 4096
#define NCOL 2048

#define BM 128        // chains per block (slab)
#define KC 32         // k-chunk
#define LDA 40        // padded LDS row (shorts): 2-way bank alias only (free)
#define NSLAB 32      // 4096 / BM
#define NJT 8         // 512 / 64 j per block

__device__ __forceinline__ float fsigmoid(float x){ return 1.0f/(1.0f+__expf(-x)); }
__device__ __forceinline__ float ftanh(float x){ return 2.0f/(1.0f+__expf(-2.0f*x))-1.0f; }

__device__ __forceinline__ bool detect_bf16(const short* p) {
    bool bf = true;
    for (int i = 0; i < 64; i += 2) {
        int e = (((unsigned short)p[i]) >> 7) & 0xFF;
        if (e > 0x7B) bf = false;
    }
    return bf;
}

// ---------------------------------------------------------------------------
// W_hh -> bf16 + zero the slab flags
// ---------------------------------------------------------------------------
__global__ void conv_whh(const void* __restrict__ whhp, short* __restrict__ whh_o,
                         int* __restrict__ flags) {
    int tid = blockIdx.x * blockDim.x + threadIdx.x;
    int stride = gridDim.x * blockDim.x;
    if (tid < NSLAB * LDIM) flags[tid] = 0;
    bool bf = detect_bf16((const short*)whhp);
    if (bf) {
        const short* s = (const short*)whhp;
        for (int i = tid; i < NCOL * HDIM; i += stride) whh_o[i] = s[i];
    } else {
        const float* s = (const float*)whhp;
        for (int i = tid; i < NCOL * HDIM; i += stride)
            ((__hip_bfloat16*)whh_o)[i] = __float2bfloat16(s[i]);
    }
}

// ---------------------------------------------------------------------------
// xg_p[id][j*4+g] = emb[id].W_ih[g*512+j] + b_ih + b_hh  (bf16, gate-interleaved)
// ---------------------------------------------------------------------------
__global__ void build_xg(const void* __restrict__ embp, const void* __restrict__ wihp,
                         const void* __restrict__ bihp, const void* __restrict__ bhhp,
                         short* __restrict__ xgp)
{
    __shared__ float es[16][EDIM];
    __shared__ float wsm[32][EDIM + 1];
    bool bf = detect_bf16((const short*)wihp);
    const int idt = blockIdx.x, ct = blockIdx.y, tt = threadIdx.x;

    if (bf) {
        const __hip_bfloat16* e = (const __hip_bfloat16*)embp;
        const __hip_bfloat16* wv = (const __hip_bfloat16*)wihp;
        for (int p = 0; p < 16; ++p) es[p][tt] = __bfloat162float(e[(idt*16+p)*EDIM + tt]);
        for (int p = 0; p < 32; ++p) wsm[p][tt] = __bfloat162float(wv[(ct*32+p)*EDIM + tt]);
    } else {
        const float* e = (const float*)embp;
        const float* wv = (const float*)wihp;
        for (int p = 0; p < 16; ++p) es[p][tt] = e[(idt*16+p)*EDIM + tt];
        for (int p = 0; p < 32; ++p) wsm[p][tt] = wv[(ct*32+p)*EDIM + tt];
    }
    __syncthreads();

    const int col_l = tt & 31, grp = tt >> 5;
    const int col = ct * 32 + col_l;          // gate-major column
    const int g = col >> 9, j = col & 511;
    float bsum = bf ? (__bfloat162float(((const __hip_bfloat16*)bihp)[col]) +
                       __bfloat162float(((const __hip_bfloat16*)bhhp)[col]))
                    : (((const float*)bihp)[col] + ((const float*)bhhp)[col]);
    float a0 = 0.f, a1 = 0.f;
    for (int k = 0; k < EDIM; ++k) {
        float wv = wsm[col_l][k];
        a0 += es[grp*2+0][k] * wv;
        a1 += es[grp*2+1][k] * wv;
    }
    ((__hip_bfloat16*)xgp)[(idt*16 + grp*2 + 0)*NCOL + j*4 + g] = __float2bfloat16(a0 + bsum);
    ((__hip_bfloat16*)xgp)[(idt*16 + grp*2 + 1)*NCOL + j*4 + g] = __float2bfloat16(a1 + bsum);
}

// ---------------------------------------------------------------------------
// Persistent LSTM: one launch, t inside. 256 blocks x 512 thr (1 block/CU).
// Block (mt,jt): 128 chains x 64 j x 4 gates. c/h_prev in REGISTERS.
// Slab flag pipeline: step t waits for flags[mt][t-1]==8 (the 8 jt-peers).
// XCD-local: slab mt entirely on XCD id&7.
// ---------------------------------------------------------------------------
__launch_bounds__(512, 2)
__global__ void lstm_persist(const int* __restrict__ seq, const int* __restrict__ lens,
                             const short* __restrict__ whh,  // bf16 [2048][512]
                             const short* __restrict__ xgp,  // bf16 [256][2048] perm
                             short* __restrict__ hb0, short* __restrict__ hb1,
                             float* __restrict__ out,        // fp32 [4096][512]
                             int* __restrict__ flags)        // [32][16]
{
    __shared__ short Asm[2][BM * LDA];        // 20 KB
    __shared__ short Bsm[2][4 * 64 * LDA];    // 40 KB

    const int id = blockIdx.x;
    const int lid = id >> 3;
    const int mt = (id & 7) * 4 + (lid & 3);   // 0..31 (XCD-local slab)
    const int jt = lid >> 2;                   // 0..7
    const int tid = threadIdx.x;
    const int wave = tid >> 6, lane = tid & 63;
    const int q = lane >> 4, ln = lane & 15;
    const int ms = wave & 1, ns = wave >> 1;   // ms 0..1, ns 0..3
    const int jloc = ns * 16 + ln;             // 0..63
    const int j = jt * 64 + jloc;              // global hidden unit

    int lns_r[16];
    float c_reg[16], h_reg[16];
#pragma unroll
    for (int i = 0; i < 16; ++i) {
        int mf = i >> 2, r = i & 3;
        lns_r[i] = lens[mt*BM + ms*64 + mf*16 + q*4 + r];
        c_reg[i] = 0.f; h_reg[i] = 0.f;
    }

    // staging indices (constant over chunks/steps)
    const int rowA = tid >> 2, segA = tid & 3;                 // A: 128x4 tasks
    const int rB0 = tid >> 2, sB = tid & 3;                    // B: 256x4 tasks
    const int rB1 = rB0 + 128;
    const long wofs0 = (long)((rB0 >> 6) * HDIM + jt * 64 + (rB0 & 63)) * HDIM;
    const long wofs1 = (long)((rB1 >> 6) * HDIM + jt * 64 + (rB1 & 63)) * HDIM;

    for (int t = 0; t < LDIM; ++t) {
        const short* hread = (t & 1) ? hb0 : hb1;   // written at t-1
        short* hwrite      = (t & 1) ? hb1 : hb0;

        // preload ids for this step (latency hides under GEMM)
        int ids[16];
#pragma unroll
        for (int i = 0; i < 16; ++i) {
            int mf = i >> 2, r = i & 3;
            ids[i] = seq[(mt*BM + ms*64 + mf*16 + q*4 + r)*LDIM + t];
        }

        floatx4 acc[4][4];
#pragma unroll
        for (int g = 0; g < 4; ++g)
#pragma unroll
            for (int mf = 0; mf < 4; ++mf) acc[g][mf] = (floatx4){0.f,0.f,0.f,0.f};

        if (t > 0) {
            if (tid == 0) {
                while (__hip_atomic_load(&flags[mt*LDIM + (t-1)], __ATOMIC_ACQUIRE,
                                         __HIP_MEMORY_SCOPE_AGENT) < NJT) {}
            }
            __syncthreads();

            // stage chunk 0
            *(short8*)&Asm[0][rowA*LDA + segA*8] =
                *(const short8*)(hread + (mt*BM + rowA)*HDIM + segA*8);
            *(short8*)&Bsm[0][rB0*LDA + sB*8] = *(const short8*)(whh + wofs0 + sB*8);
            *(short8*)&Bsm[0][rB1*LDA + sB*8] = *(const short8*)(whh + wofs1 + sB*8);
            __syncthreads();

            for (int kc = 0; kc < 16; ++kc) {
                const int b = kc & 1;
                if (kc < 15) {
                    const int k0 = (kc + 1) * KC;
                    *(short8*)&Asm[b^1][rowA*LDA + segA*8] =
                        *(const short8*)(hread + (mt*BM + rowA)*HDIM + k0 + segA*8);
                    *(short8*)&Bsm[b^1][rB0*LDA + sB*8] =
                        *(const short8*)(whh + wofs0 + k0 + sB*8);
                    *(short8*)&Bsm[b^1][rB1*LDA + sB*8] =
                        *(const short8*)(whh + wofs1 + k0 + sB*8);
                }
                short8 af[4], bfr[4];
#pragma unroll
                for (int mf = 0; mf < 4; ++mf)
                    af[mf] = *(const short8*)&Asm[b][(ms*64 + mf*16 + ln)*LDA + q*8];
#pragma unroll
                for (int g = 0; g < 4; ++g)
                    bfr[g] = *(const short8*)&Bsm[b][(g*64 + jloc)*LDA + q*8];
#pragma unroll
                for (int g = 0; g < 4; ++g)
#pragma unroll
                    for (int mf = 0; mf < 4; ++mf)
                        acc[g][mf] = __builtin_amdgcn_mfma_f32_16x16x32_bf16(
                            af[mf], bfr[g], acc[g][mf], 0, 0, 0);
                __syncthreads();
            }
        }

        // ---- epilogue: issue all xg gathers, then cell updates ----
        short4v xv[16];
#pragma unroll
        for (int i = 0; i < 16; ++i)
            xv[i] = *(const short4v*)(xgp + (long)ids[i]*NCOL + j*4);

        const bool last = (t == LDIM - 1);
#pragma unroll
        for (int mf = 0; mf < 4; ++mf)
#pragma unroll
            for (int r = 0; r < 4; ++r) {
                const int i = mf*4 + r;
                const int chain = mt*BM + ms*64 + mf*16 + q*4 + r;
                float pre[4];
#pragma unroll
                for (int g = 0; g < 4; ++g) {
                    unsigned int u = ((unsigned int)(unsigned short)xv[i][g]) << 16;
                    pre[g] = acc[g][mf][r] + __uint_as_float(u);
                }
                float ig = fsigmoid(pre[0]);
                float fg = fsigmoid(pre[1]);
                float gg = ftanh(pre[2]);
                float og = fsigmoid(pre[3]);
                float c_new = fg * c_reg[i] + ig * gg;
                float h_new = og * ftanh(c_new);
                bool mk = lns_r[i] > t;
                float h_st = mk ? h_new : h_reg[i];
                c_reg[i] = mk ? c_new : c_reg[i];
                h_reg[i] = h_st;
                if (last) {
                    out[(long)chain*HDIM + j] = h_st;
                } else {
                    ((__hip_bfloat16*)hwrite)[(long)chain*HDIM + j] = __float2bfloat16(h_st);
                }
            }

        if (!last) {
            __syncthreads();   // all h stores of this block drained (vmcnt(0))
            if (tid == 0) {
                __hip_atomic_fetch_add(&flags[mt*LDIM + t], 1, __ATOMIC_RELEASE,
                                       __HIP_MEMORY_SCOPE_AGENT);
            }
        }
    }
}

extern "C" void kernel_launch(void* const* d_in, const int* in_sizes, int n_in,
                              void* d_out, int out_size, void* d_ws, size_t ws_size,
                              hipStream_t stream) {
    const int* seq  = (const int*)d_in[0];
    const int* lens = (const int*)d_in[1];

    // ws: hb0 4M | hb1 4M | xg_p 1M | whh_bf 2M | flags 2K
    char* w = (char*)d_ws;
    short* hb0    = (short*)w;
    short* hb1    = (short*)(w + 4u*1024*1024);
    short* xgp    = (short*)(w + 8u*1024*1024);
    short* whh_bf = (short*)(w + 9u*1024*1024);
    int*   flags  = (int*)(w + 11u*1024*1024);
    float* out = (float*)d_out;

    conv_whh<<<512, 256, 0, stream>>>(d_in[4], whh_bf, flags);
    build_xg<<<dim3(16, 64), 256, 0, stream>>>(d_in[2], d_in[3], d_in[5], d_in[6], xgp);

    void* args[] = {(void*)&seq, (void*)&lens, (void*)&whh_bf, (void*)&xgp,
                    (void*)&hb0, (void*)&hb1, (void*)&out, (void*)&flags};
    hipError_t e = hipLaunchCooperativeKernel((const void*)lstm_persist,
                                              dim3(256), dim3(512), args, 0, stream);
    if (e != hipSuccess) {
        (void)hipGetLastError();  // clear sticky error, use regular launch:
        // 256 blocks at 1 block/CU are trivially co-resident on 256 CUs.
        lstm_persist<<<dim3(256), dim3(512), 0, stream>>>(seq, lens, whh_bf, xgp,
                                                          hb0, hb1, out, flags);
    }
}